// Round 1
// baseline (2094.447 us; speedup 1.0000x reference)
//
#include <hip/hip_runtime.h>
#include <hip/hip_bf16.h>

#define NN 50000
#define EE 1600000
#define DIN 768
#define NH 256

typedef unsigned short u16;
typedef unsigned int u32;

__device__ __forceinline__ float bf2f(u16 u) {
  union { u32 i; float f; } x; x.i = ((u32)u) << 16; return x.f;
}

// ---------------- CSR build ----------------
// grid covers exactly 2E threads (12500 x 256)
__global__ void hist_kernel(const int* __restrict__ rA, const int* __restrict__ rB,
                            int* __restrict__ cntA, int* __restrict__ cntB) {
  int e = blockIdx.x * 256 + threadIdx.x;
  if (e < EE) atomicAdd(&cntA[rA[e]], 1);
  else        atomicAdd(&cntB[rB[e - EE]], 1);
}

// 2 blocks x 1024 threads: block 0 scans CSR-A counts, block 1 CSR-B.
// In-place: cnt[i] becomes the exclusive prefix (cursor), rs[i+1] = inclusive.
__global__ void scan_kernel(int* __restrict__ cntA, int* __restrict__ rsA,
                            int* __restrict__ cntB, int* __restrict__ rsB, int n) {
  int* cnt = (blockIdx.x == 0) ? cntA : cntB;
  int* rs  = (blockIdx.x == 0) ? rsA  : rsB;
  __shared__ int wsum[16];
  int tid = threadIdx.x, lane = tid & 63, wid = tid >> 6;
  int carry = 0;
  if (tid == 0) rs[0] = 0;
  for (int base = 0; base < n; base += 1024) {
    int i = base + tid;
    int v = (i < n) ? cnt[i] : 0;
    int s = v;
#pragma unroll
    for (int off = 1; off < 64; off <<= 1) {
      int t = __shfl_up(s, off, 64);
      if (lane >= off) s += t;
    }
    if (lane == 63) wsum[wid] = s;
    __syncthreads();
    int wtot = 0;
    for (int w = 0; w < wid; ++w) wtot += wsum[w];
    int incl = carry + wtot + s;
    if (i < n) { rs[i + 1] = incl; cnt[i] = incl - v; }
    int total = 0;
    for (int w = 0; w < 16; ++w) total += wsum[w];
    carry += total;
    __syncthreads();
  }
}

__global__ void scatter_kernel(const int* __restrict__ rA, const int* __restrict__ cA, const float* __restrict__ vA,
                               const int* __restrict__ rB, const int* __restrict__ cB, const float* __restrict__ vB,
                               int* __restrict__ curA, int* __restrict__ colA, float* __restrict__ valA,
                               int* __restrict__ curB, int* __restrict__ colB, float* __restrict__ valB) {
  int e = blockIdx.x * 256 + threadIdx.x;
  if (e < EE) {
    int r = rA[e];
    int p = atomicAdd(&curA[r], 1);
    colA[p] = cA[e]; valA[p] = vA[e];
  } else {
    e -= EE;
    int r = rB[e];
    int p = atomicAdd(&curB[r], 1);
    colB[p] = cB[e]; valB[p] = vB[e];
  }
}

// ---------------- Layer-1 dense GEMMs ----------------
// X [M,768] fp32 @ W [768,256] fp32 -> bf16 [M,256]; z=2 adds bias+tanh.
// 64x64 tile, BK=16, 256 threads, 4x4 micro-tile.
#define BM 64
#define BN 64
#define BK 16
#define LDP 68   // padded row stride in floats (16B-aligned, breaks pow2)

__global__ __launch_bounds__(256) void gemm_l1(
    const float* __restrict__ X,
    const float* __restrict__ Wa, const float* __restrict__ Wb, const float* __restrict__ Wc,
    const float* __restrict__ bc,
    __hip_bfloat16* __restrict__ Oa, __hip_bfloat16* __restrict__ Ob, __hip_bfloat16* __restrict__ Oc) {
  const float* W;
  __hip_bfloat16* O;
  int act = 0;
  if (blockIdx.z == 0)      { W = Wa; O = Oa; }
  else if (blockIdx.z == 1) { W = Wb; O = Ob; }
  else                      { W = Wc; O = Oc; act = 1; }

  __shared__ float As[BK][BM + 4];  // [k][m]
  __shared__ float Bs[BK][BN + 4];  // [k][n]

  int tx = threadIdx.x & 15, ty = threadIdx.x >> 4;
  int rowBase = blockIdx.y * BM;
  int colBase = blockIdx.x * BN;

  // A-load: thread -> row=tid>>2 (0..63), k4=(tid&3)*4
  int la_r = threadIdx.x >> 2;
  int la_k = (threadIdx.x & 3) * 4;
  // B-load: thread -> k=tid>>4 (0..15), c4=(tid&15)*4
  int lb_k = threadIdx.x >> 4;
  int lb_c = (threadIdx.x & 15) * 4;

  float acc[4][4] = {};

  for (int k0 = 0; k0 < DIN; k0 += BK) {
    int gr = rowBase + la_r;
    float4 av;
    if (gr < NN) av = *reinterpret_cast<const float4*>(X + (size_t)gr * DIN + k0 + la_k);
    else         av = make_float4(0.f, 0.f, 0.f, 0.f);
    As[la_k + 0][la_r] = av.x;
    As[la_k + 1][la_r] = av.y;
    As[la_k + 2][la_r] = av.z;
    As[la_k + 3][la_r] = av.w;
    float4 bv = *reinterpret_cast<const float4*>(W + (size_t)(k0 + lb_k) * NH + colBase + lb_c);
    *reinterpret_cast<float4*>(&Bs[lb_k][lb_c]) = bv;
    __syncthreads();
#pragma unroll
    for (int kk = 0; kk < BK; ++kk) {
      float4 a = *reinterpret_cast<const float4*>(&As[kk][ty * 4]);
      float4 b = *reinterpret_cast<const float4*>(&Bs[kk][tx * 4]);
      float aa[4] = {a.x, a.y, a.z, a.w};
      float bb[4] = {b.x, b.y, b.z, b.w};
#pragma unroll
      for (int i = 0; i < 4; ++i)
#pragma unroll
        for (int j = 0; j < 4; ++j) acc[i][j] += aa[i] * bb[j];
    }
    __syncthreads();
  }

#pragma unroll
  for (int i = 0; i < 4; ++i) {
    int r = rowBase + ty * 4 + i;
    if (r >= NN) continue;
#pragma unroll
    for (int j = 0; j < 4; ++j) {
      int c = colBase + tx * 4 + j;
      float v = acc[i][j];
      if (act) v = tanhf(v + bc[c]);
      O[(size_t)r * NH + c] = __float2bfloat16(v);
    }
  }
}

// ---------------- SpMM over H=256 ----------------
// one block (256 threads) per row; out[n,h] = bias[h] + sum_e val*H[col,h]
__global__ __launch_bounds__(256) void spmm_h(
    const int* __restrict__ rs, const int* __restrict__ col, const float* __restrict__ val,
    const __hip_bfloat16* __restrict__ H, const float* __restrict__ bias,
    __hip_bfloat16* __restrict__ out) {
  int n = blockIdx.x;
  int h = threadIdx.x;
  int s = rs[n], e = rs[n + 1];
  float acc = bias[h];
  const u16* Hu = reinterpret_cast<const u16*>(H);
  for (int i = s; i < e; ++i) {
    int c = col[i];
    float v = val[i];
    acc += v * bf2f(Hu[(size_t)c * NH + h]);
  }
  out[(size_t)n * NH + h] = __float2bfloat16(acc);
}

// ---------------- attention fusion ----------------
// per node: l_j = sum_h R1*w[h,j] + R2*w[256+h,j] + T*w[512+h,j]
// a = softmax(|l|); X1 = a0*R1 + a1*R2 + a2*T (written over R1 buffer)
__global__ __launch_bounds__(256) void fusion_kernel(
    const __hip_bfloat16* __restrict__ R1, const __hip_bfloat16* __restrict__ R2,
    const __hip_bfloat16* __restrict__ T, const float* __restrict__ afw,
    __hip_bfloat16* __restrict__ X1) {
  __shared__ float w[DIN * 3];
  int tid = threadIdx.x;
  for (int i = tid; i < DIN * 3; i += 256) w[i] = afw[i];
  __syncthreads();
  int lane = tid & 63, wave = tid >> 6;
  int n = blockIdx.x * 4 + wave;  // 12500*4 = 50000 exact
  int h0 = lane * 4;
  const u16* r1p = reinterpret_cast<const u16*>(R1) + (size_t)n * NH + h0;
  const u16* r2p = reinterpret_cast<const u16*>(R2) + (size_t)n * NH + h0;
  const u16* tp  = reinterpret_cast<const u16*>(T)  + (size_t)n * NH + h0;
  ushort4 r1v = *reinterpret_cast<const ushort4*>(r1p);
  ushort4 r2v = *reinterpret_cast<const ushort4*>(r2p);
  ushort4 tv  = *reinterpret_cast<const ushort4*>(tp);
  float r1[4] = {bf2f(r1v.x), bf2f(r1v.y), bf2f(r1v.z), bf2f(r1v.w)};
  float r2[4] = {bf2f(r2v.x), bf2f(r2v.y), bf2f(r2v.z), bf2f(r2v.w)};
  float t[4]  = {bf2f(tv.x),  bf2f(tv.y),  bf2f(tv.z),  bf2f(tv.w)};
  float l0 = 0.f, l1 = 0.f, l2 = 0.f;
#pragma unroll
  for (int i = 0; i < 4; ++i) {
    int h = h0 + i;
    l0 += r1[i] * w[h * 3 + 0] + r2[i] * w[(NH + h) * 3 + 0] + t[i] * w[(2 * NH + h) * 3 + 0];
    l1 += r1[i] * w[h * 3 + 1] + r2[i] * w[(NH + h) * 3 + 1] + t[i] * w[(2 * NH + h) * 3 + 1];
    l2 += r1[i] * w[h * 3 + 2] + r2[i] * w[(NH + h) * 3 + 2] + t[i] * w[(2 * NH + h) * 3 + 2];
  }
#pragma unroll
  for (int off = 32; off > 0; off >>= 1) {
    l0 += __shfl_xor(l0, off, 64);
    l1 += __shfl_xor(l1, off, 64);
    l2 += __shfl_xor(l2, off, 64);
  }
  l0 = fabsf(l0); l1 = fabsf(l1); l2 = fabsf(l2);
  float m = fmaxf(l0, fmaxf(l1, l2));
  float e0 = expf(l0 - m), e1 = expf(l1 - m), e2 = expf(l2 - m);
  float inv = 1.f / (e0 + e1 + e2);
  float a0 = e0 * inv, a1 = e1 * inv, a2 = e2 * inv;
  __hip_bfloat16* xp = X1 + (size_t)n * NH + h0;
#pragma unroll
  for (int i = 0; i < 4; ++i)
    xp[i] = __float2bfloat16(a0 * r1[i] + a1 * r2[i] + a2 * t[i]);
}

// ---------------- layer-2 GEMV (6 dots per node, K=256) ----------------
__global__ __launch_bounds__(256) void layer2_gemm(
    const __hip_bfloat16* __restrict__ X1,
    const float* __restrict__ W2r1, const float* __restrict__ W2r2,
    const float* __restrict__ mlpW, const float* __restrict__ mlpb,
    float* __restrict__ Z1, float* __restrict__ Z2, float* __restrict__ Y1) {
  __shared__ float w1[NH * 2], w2[NH * 2], wm[NH * 2];
  int tid = threadIdx.x;
  for (int i = tid; i < NH * 2; i += 256) {
    w1[i] = W2r1[i]; w2[i] = W2r2[i]; wm[i] = mlpW[i];
  }
  __syncthreads();
  int lane = tid & 63, wave = tid >> 6;
  int n = blockIdx.x * 4 + wave;
  int h0 = lane * 4;
  const u16* xp = reinterpret_cast<const u16*>(X1) + (size_t)n * NH + h0;
  ushort4 xv = *reinterpret_cast<const ushort4*>(xp);
  float x[4] = {bf2f(xv.x), bf2f(xv.y), bf2f(xv.z), bf2f(xv.w)};
  float p10 = 0.f, p11 = 0.f, p20 = 0.f, p21 = 0.f, p30 = 0.f, p31 = 0.f;
#pragma unroll
  for (int i = 0; i < 4; ++i) {
    int h = h0 + i;
    p10 += x[i] * w1[h * 2 + 0]; p11 += x[i] * w1[h * 2 + 1];
    p20 += x[i] * w2[h * 2 + 0]; p21 += x[i] * w2[h * 2 + 1];
    p30 += x[i] * wm[h * 2 + 0]; p31 += x[i] * wm[h * 2 + 1];
  }
#pragma unroll
  for (int off = 32; off > 0; off >>= 1) {
    p10 += __shfl_down(p10, off, 64); p11 += __shfl_down(p11, off, 64);
    p20 += __shfl_down(p20, off, 64); p21 += __shfl_down(p21, off, 64);
    p30 += __shfl_down(p30, off, 64); p31 += __shfl_down(p31, off, 64);
  }
  if (lane == 0) {
    Z1[n * 2 + 0] = p10; Z1[n * 2 + 1] = p11;
    Z2[n * 2 + 0] = p20; Z2[n * 2 + 1] = p21;
    Y1[n * 2 + 0] = tanhf(p30 + mlpb[0]);
    Y1[n * 2 + 1] = tanhf(p31 + mlpb[1]);
  }
}

// ---------------- layer-2 SpMM (2 cols) + final sum ----------------
__global__ __launch_bounds__(256) void spmm2_final(
    const int* __restrict__ rsA, const int* __restrict__ colA, const float* __restrict__ valA,
    const int* __restrict__ rsB, const int* __restrict__ colB, const float* __restrict__ valB,
    const float* __restrict__ Z1, const float* __restrict__ Z2, const float* __restrict__ Y1,
    const float* __restrict__ b2r1, const float* __restrict__ b2r2,
    float* __restrict__ out) {
  int tid = threadIdx.x;
  int lane = tid & 63, wave = tid >> 6;
  int n = blockIdx.x * 4 + wave;
  float a0 = 0.f, a1 = 0.f;
  {
    int s = rsA[n], e = rsA[n + 1];
    for (int i = s + lane; i < e; i += 64) {
      int c = colA[i]; float v = valA[i];
      a0 += v * Z1[c * 2 + 0];
      a1 += v * Z1[c * 2 + 1];
    }
  }
  float c0 = 0.f, c1 = 0.f;
  {
    int s = rsB[n], e = rsB[n + 1];
    for (int i = s + lane; i < e; i += 64) {
      int c = colB[i]; float v = valB[i];
      c0 += v * Z2[c * 2 + 0];
      c1 += v * Z2[c * 2 + 1];
    }
  }
#pragma unroll
  for (int off = 32; off > 0; off >>= 1) {
    a0 += __shfl_down(a0, off, 64); a1 += __shfl_down(a1, off, 64);
    c0 += __shfl_down(c0, off, 64); c1 += __shfl_down(c1, off, 64);
  }
  if (lane == 0) {
    out[n * 2 + 0] = (a0 + b2r1[0]) + (c0 + b2r2[0]) + Y1[n * 2 + 0];
    out[n * 2 + 1] = (a1 + b2r1[1]) + (c1 + b2r2[1]) + Y1[n * 2 + 1];
  }
}

extern "C" void kernel_launch(void* const* d_in, const int* in_sizes, int n_in,
                              void* d_out, int out_size, void* d_ws, size_t ws_size,
                              hipStream_t stream) {
  const float* x        = (const float*)d_in[0];
  const int*   adj_rows = (const int*)d_in[1];
  const int*   adj_cols = (const int*)d_in[2];
  const float* adj_vals = (const float*)d_in[3];
  const int*   s_rows   = (const int*)d_in[4];
  const int*   s_cols   = (const int*)d_in[5];
  const float* s_vals   = (const float*)d_in[6];
  const float* W1r1     = (const float*)d_in[7];
  const float* b1r1     = (const float*)d_in[8];
  const float* W1r2     = (const float*)d_in[9];
  const float* b1r2     = (const float*)d_in[10];
  const float* mlp1_W   = (const float*)d_in[11];
  const float* mlp1_b   = (const float*)d_in[12];
  const float* af1_w    = (const float*)d_in[13];
  const float* W2r1     = (const float*)d_in[14];
  const float* b2r1     = (const float*)d_in[15];
  const float* W2r2     = (const float*)d_in[16];
  const float* b2r2     = (const float*)d_in[17];
  const float* mlp2_W   = (const float*)d_in[18];
  const float* mlp2_b   = (const float*)d_in[19];
  float* out = (float*)d_out;

  char* p = (char*)d_ws;
  auto alloc = [&](size_t b) { char* r = p; p += (b + 255) & ~(size_t)255; return r; };

  __hip_bfloat16* H1 = (__hip_bfloat16*)alloc((size_t)NN * NH * 2);
  __hip_bfloat16* H2 = (__hip_bfloat16*)alloc((size_t)NN * NH * 2);
  __hip_bfloat16* T  = (__hip_bfloat16*)alloc((size_t)NN * NH * 2);
  __hip_bfloat16* R1 = (__hip_bfloat16*)alloc((size_t)NN * NH * 2);  // fusion writes X1 here
  __hip_bfloat16* R2 = (__hip_bfloat16*)alloc((size_t)NN * NH * 2);
  int*   rsA  = (int*)alloc((size_t)(NN + 1) * 4);
  int*   curA = (int*)alloc((size_t)NN * 4);
  int*   colA = (int*)alloc((size_t)EE * 4);
  float* valA = (float*)alloc((size_t)EE * 4);
  int*   rsB  = (int*)alloc((size_t)(NN + 1) * 4);
  int*   curB = (int*)alloc((size_t)NN * 4);
  int*   colB = (int*)alloc((size_t)EE * 4);
  float* valB = (float*)alloc((size_t)EE * 4);
  float* Z1 = (float*)alloc((size_t)NN * 2 * 4);
  float* Z2 = (float*)alloc((size_t)NN * 2 * 4);
  float* Y1 = (float*)alloc((size_t)NN * 2 * 4);

  // CSR build
  hipMemsetAsync(curA, 0, (size_t)NN * 4, stream);
  hipMemsetAsync(curB, 0, (size_t)NN * 4, stream);
  hist_kernel<<<12500, 256, 0, stream>>>(adj_rows, s_rows, curA, curB);
  scan_kernel<<<2, 1024, 0, stream>>>(curA, rsA, curB, rsB, NN);
  scatter_kernel<<<12500, 256, 0, stream>>>(adj_rows, adj_cols, adj_vals,
                                            s_rows, s_cols, s_vals,
                                            curA, colA, valA, curB, colB, valB);

  // layer-1 dense GEMMs (H1, H2 raw; T = tanh(x@mlp1_W + mlp1_b))
  dim3 g1(NH / BN, (NN + BM - 1) / BM, 3);
  gemm_l1<<<g1, 256, 0, stream>>>(x, W1r1, W1r2, mlp1_W, mlp1_b, H1, H2, T);

  // layer-1 SpMMs (+bias)
  spmm_h<<<NN, 256, 0, stream>>>(rsA, colA, valA, H1, b1r1, R1);
  spmm_h<<<NN, 256, 0, stream>>>(rsB, colB, valB, H2, b1r2, R2);

  // attention fusion -> X1 (overwrites R1)
  fusion_kernel<<<NN / 4, 256, 0, stream>>>(R1, R2, T, af1_w, R1);

  // layer-2 dense part
  layer2_gemm<<<NN / 4, 256, 0, stream>>>(R1, W2r1, W2r2, mlp2_W, mlp2_b, Z1, Z2, Y1);

  // layer-2 SpMMs + final sum
  spmm2_final<<<NN / 4, 256, 0, stream>>>(rsA, colA, valA, rsB, colB, valB,
                                          Z1, Z2, Y1, b2r1, b2r2, out);
}

// Round 2
// 1468.231 us; speedup vs baseline: 1.4265x; 1.4265x over previous
//
#include <hip/hip_runtime.h>
#include <hip/hip_bf16.h>

#define NN 50000
#define EE 1600000
#define DIN 768
#define NH 256

typedef unsigned short u16;
typedef unsigned int u32;

__device__ __forceinline__ float bf2f(u16 u) {
  union { u32 i; float f; } x; x.i = ((u32)u) << 16; return x.f;
}
__device__ __forceinline__ u16 f2bf(float f) {
  union { float f; u32 u; } x; x.f = f;
  u32 r = x.u + 0x7fff + ((x.u >> 16) & 1);  // RNE
  return (u16)(r >> 16);
}

// ---------------- CSR build ----------------
__global__ void hist_kernel(const int* __restrict__ rA, const int* __restrict__ rB,
                            int* __restrict__ cntA, int* __restrict__ cntB) {
  int e = blockIdx.x * 256 + threadIdx.x;
  if (e < EE) atomicAdd(&cntA[rA[e]], 1);
  else        atomicAdd(&cntB[rB[e - EE]], 1);
}

__global__ void scan_kernel(int* __restrict__ cntA, int* __restrict__ rsA,
                            int* __restrict__ cntB, int* __restrict__ rsB, int n) {
  int* cnt = (blockIdx.x == 0) ? cntA : cntB;
  int* rs  = (blockIdx.x == 0) ? rsA  : rsB;
  __shared__ int wsum[16];
  int tid = threadIdx.x, lane = tid & 63, wid = tid >> 6;
  int carry = 0;
  if (tid == 0) rs[0] = 0;
  for (int base = 0; base < n; base += 1024) {
    int i = base + tid;
    int v = (i < n) ? cnt[i] : 0;
    int s = v;
#pragma unroll
    for (int off = 1; off < 64; off <<= 1) {
      int t = __shfl_up(s, off, 64);
      if (lane >= off) s += t;
    }
    if (lane == 63) wsum[wid] = s;
    __syncthreads();
    int wtot = 0;
    for (int w = 0; w < wid; ++w) wtot += wsum[w];
    int incl = carry + wtot + s;
    if (i < n) { rs[i + 1] = incl; cnt[i] = incl - v; }
    int total = 0;
    for (int w = 0; w < 16; ++w) total += wsum[w];
    carry += total;
    __syncthreads();
  }
}

__global__ void scatter_kernel(const int* __restrict__ rA, const int* __restrict__ cA, const float* __restrict__ vA,
                               const int* __restrict__ rB, const int* __restrict__ cB, const float* __restrict__ vB,
                               int* __restrict__ curA, int* __restrict__ colA, float* __restrict__ valA,
                               int* __restrict__ curB, int* __restrict__ colB, float* __restrict__ valB) {
  int e = blockIdx.x * 256 + threadIdx.x;
  if (e < EE) {
    int r = rA[e];
    int p = atomicAdd(&curA[r], 1);
    colA[p] = cA[e]; valA[p] = vA[e];
  } else {
    e -= EE;
    int r = rB[e];
    int p = atomicAdd(&curB[r], 1);
    colB[p] = cB[e]; valB[p] = vB[e];
  }
}

// ---------------- prep: X fp32 -> bf16 ----------------
// 37500 blocks x 256 threads, 4 elements each: exactly NN*DIN
__global__ __launch_bounds__(256) void convert_x(const float* __restrict__ X, u16* __restrict__ Xb) {
  size_t idx = (size_t)blockIdx.x * 256 + threadIdx.x;
  float4 v = reinterpret_cast<const float4*>(X)[idx];
  ushort4 o;
  o.x = f2bf(v.x); o.y = f2bf(v.y); o.z = f2bf(v.z); o.w = f2bf(v.w);
  reinterpret_cast<ushort4*>(Xb)[idx] = o;
}

// ---------------- prep: pack + transpose weights ----------------
// Wt[n][k] = W_{n/256}[k][n%256], n,k in [0,768). 2304 blocks x 256.
__global__ __launch_bounds__(256) void pack_wt(const float* __restrict__ Wa, const float* __restrict__ Wb,
                                               const float* __restrict__ Wc, u16* __restrict__ Wt) {
  int idx = blockIdx.x * 256 + threadIdx.x;
  int n = idx / DIN, k = idx - n * DIN;
  const float* W = (n < 256) ? Wa : (n < 512) ? Wb : Wc;
  Wt[idx] = f2bf(W[(size_t)k * NH + (n & 255)]);
}

// ---------------- Layer-1 fused MFMA GEMM ----------------
// C[50000 x 768] = Xb[50000 x 768] @ Wcat; N-split: [0,256)->H1, [256,512)->H2,
// [512,768)->tanh(.+mlp1_b)->T. 128x128 tile, BK=32, 16x16x32 bf16 MFMA.
#define TM 128
#define TN 128
#define TK 32

typedef __attribute__((ext_vector_type(8))) short short8;
typedef __attribute__((ext_vector_type(4))) float f32x4;

__device__ __forceinline__ void gload16(const u16* g, u16* lds) {
  __builtin_amdgcn_global_load_lds((const __attribute__((address_space(1))) unsigned int*)g,
                                   (__attribute__((address_space(3))) unsigned int*)lds, 16, 0, 0);
}

__global__ __launch_bounds__(256) void gemm_mfma(
    const u16* __restrict__ Xb, const u16* __restrict__ Wt, const float* __restrict__ mlp1_b,
    u16* __restrict__ H1, u16* __restrict__ H2, u16* __restrict__ T) {
  __shared__ u16 As[TM * TK];   // [m][k-swizzled], 8 KB
  __shared__ u16 Bs[TN * TK];   // [n][k-swizzled], 8 KB

  const int tid = threadIdx.x;
  const int lane = tid & 63;
  const int w = tid >> 6;        // wave 0..3
  const int m0 = blockIdx.y * TM;
  const int n0 = blockIdx.x * TN;
  const int wm = w >> 1, wn = w & 1;   // 2x2 wave grid, 64x64 each

  f32x4 acc[4][4] = {};

  // staging: per wave-issue, 16 rows x 32 k (1 KB); lane i -> row i/4, phys kchunk i%4
  const int r_l = lane >> 2;
  const int kcp = lane & 3;

  // fragment read indices
  const int r16 = lane & 15;
  const int kcl = lane >> 4;

  for (int k0 = 0; k0 < DIN; k0 += TK) {
#pragma unroll
    for (int q = 0; q < 2; ++q) {
      int row = w * 32 + q * 16 + r_l;                  // 0..127
      int kc = kcp ^ ((row >> 1) & 3);                  // logical k-chunk (bank swizzle)
      int gr = m0 + row; if (gr >= NN) gr = NN - 1;     // clamp tail (safe: only feeds dead C rows)
      gload16(Xb + (size_t)gr * DIN + k0 + kc * 8, &As[(w * 32 + q * 16) * TK]);
      gload16(Wt + (size_t)(n0 + row) * DIN + k0 + kc * 8, &Bs[(w * 32 + q * 16) * TK]);
    }
    __syncthreads();

    short8 aF[4], bF[4];
#pragma unroll
    for (int i = 0; i < 4; ++i) {
      int m = wm * 64 + i * 16 + r16;
      aF[i] = *reinterpret_cast<const short8*>(&As[m * TK + (kcl ^ ((m >> 1) & 3)) * 8]);
      int n = wn * 64 + i * 16 + r16;
      bF[i] = *reinterpret_cast<const short8*>(&Bs[n * TK + (kcl ^ ((n >> 1) & 3)) * 8]);
    }
#pragma unroll
    for (int i = 0; i < 4; ++i)
#pragma unroll
      for (int j = 0; j < 4; ++j)
        acc[i][j] = __builtin_amdgcn_mfma_f32_16x16x32_bf16(aF[i], bF[j], acc[i][j], 0, 0, 0);
    __syncthreads();
  }

  // epilogue: C/D layout col=lane&15, row=(lane>>4)*4+r
  const int bsel = n0 >> 8;
  u16* O = (bsel == 0) ? H1 : (bsel == 1) ? H2 : T;
  const int act = (bsel == 2);
  const int cb = n0 & 255;
  const int rq = lane >> 4;
#pragma unroll
  for (int i = 0; i < 4; ++i) {
#pragma unroll
    for (int r = 0; r < 4; ++r) {
      int grow = m0 + wm * 64 + i * 16 + rq * 4 + r;
      if (grow >= NN) continue;
#pragma unroll
      for (int j = 0; j < 4; ++j) {
        int c = cb + wn * 64 + j * 16 + r16;
        float v = acc[i][j][r];
        if (act) v = tanhf(v + mlp1_b[c]);
        O[(size_t)grow * NH + c] = f2bf(v);
      }
    }
  }
}

// ---------------- SpMM over H=256 ----------------
__global__ __launch_bounds__(256) void spmm_h(
    const int* __restrict__ rs, const int* __restrict__ col, const float* __restrict__ val,
    const u16* __restrict__ H, const float* __restrict__ bias,
    u16* __restrict__ out) {
  int n = blockIdx.x;
  int h = threadIdx.x;
  int s = rs[n], e = rs[n + 1];
  float acc = bias[h];
  for (int i = s; i < e; ++i) {
    int c = col[i];
    float v = val[i];
    acc += v * bf2f(H[(size_t)c * NH + h]);
  }
  out[(size_t)n * NH + h] = f2bf(acc);
}

// ---------------- attention fusion ----------------
__global__ __launch_bounds__(256) void fusion_kernel(
    const u16* __restrict__ R1, const u16* __restrict__ R2,
    const u16* __restrict__ T, const float* __restrict__ afw,
    u16* __restrict__ X1) {
  __shared__ float w[DIN * 3];
  int tid = threadIdx.x;
  for (int i = tid; i < DIN * 3; i += 256) w[i] = afw[i];
  __syncthreads();
  int lane = tid & 63, wave = tid >> 6;
  int n = blockIdx.x * 4 + wave;
  int h0 = lane * 4;
  ushort4 r1v = *reinterpret_cast<const ushort4*>(R1 + (size_t)n * NH + h0);
  ushort4 r2v = *reinterpret_cast<const ushort4*>(R2 + (size_t)n * NH + h0);
  ushort4 tv  = *reinterpret_cast<const ushort4*>(T  + (size_t)n * NH + h0);
  float r1[4] = {bf2f(r1v.x), bf2f(r1v.y), bf2f(r1v.z), bf2f(r1v.w)};
  float r2[4] = {bf2f(r2v.x), bf2f(r2v.y), bf2f(r2v.z), bf2f(r2v.w)};
  float t[4]  = {bf2f(tv.x),  bf2f(tv.y),  bf2f(tv.z),  bf2f(tv.w)};
  float l0 = 0.f, l1 = 0.f, l2 = 0.f;
#pragma unroll
  for (int i = 0; i < 4; ++i) {
    int h = h0 + i;
    l0 += r1[i] * w[h * 3 + 0] + r2[i] * w[(NH + h) * 3 + 0] + t[i] * w[(2 * NH + h) * 3 + 0];
    l1 += r1[i] * w[h * 3 + 1] + r2[i] * w[(NH + h) * 3 + 1] + t[i] * w[(2 * NH + h) * 3 + 1];
    l2 += r1[i] * w[h * 3 + 2] + r2[i] * w[(NH + h) * 3 + 2] + t[i] * w[(2 * NH + h) * 3 + 2];
  }
#pragma unroll
  for (int off = 32; off > 0; off >>= 1) {
    l0 += __shfl_xor(l0, off, 64);
    l1 += __shfl_xor(l1, off, 64);
    l2 += __shfl_xor(l2, off, 64);
  }
  l0 = fabsf(l0); l1 = fabsf(l1); l2 = fabsf(l2);
  float m = fmaxf(l0, fmaxf(l1, l2));
  float e0 = expf(l0 - m), e1 = expf(l1 - m), e2 = expf(l2 - m);
  float inv = 1.f / (e0 + e1 + e2);
  float a0 = e0 * inv, a1 = e1 * inv, a2 = e2 * inv;
  u16* xp = X1 + (size_t)n * NH + h0;
#pragma unroll
  for (int i = 0; i < 4; ++i)
    xp[i] = f2bf(a0 * r1[i] + a1 * r2[i] + a2 * t[i]);
}

// ---------------- layer-2 GEMV (6 dots per node, K=256) ----------------
__global__ __launch_bounds__(256) void layer2_gemm(
    const u16* __restrict__ X1,
    const float* __restrict__ W2r1, const float* __restrict__ W2r2,
    const float* __restrict__ mlpW, const float* __restrict__ mlpb,
    float* __restrict__ Z1, float* __restrict__ Z2, float* __restrict__ Y1) {
  __shared__ float w1[NH * 2], w2[NH * 2], wm[NH * 2];
  int tid = threadIdx.x;
  for (int i = tid; i < NH * 2; i += 256) {
    w1[i] = W2r1[i]; w2[i] = W2r2[i]; wm[i] = mlpW[i];
  }
  __syncthreads();
  int lane = tid & 63, wave = tid >> 6;
  int n = blockIdx.x * 4 + wave;
  int h0 = lane * 4;
  ushort4 xv = *reinterpret_cast<const ushort4*>(X1 + (size_t)n * NH + h0);
  float x[4] = {bf2f(xv.x), bf2f(xv.y), bf2f(xv.z), bf2f(xv.w)};
  float p10 = 0.f, p11 = 0.f, p20 = 0.f, p21 = 0.f, p30 = 0.f, p31 = 0.f;
#pragma unroll
  for (int i = 0; i < 4; ++i) {
    int h = h0 + i;
    p10 += x[i] * w1[h * 2 + 0]; p11 += x[i] * w1[h * 2 + 1];
    p20 += x[i] * w2[h * 2 + 0]; p21 += x[i] * w2[h * 2 + 1];
    p30 += x[i] * wm[h * 2 + 0]; p31 += x[i] * wm[h * 2 + 1];
  }
#pragma unroll
  for (int off = 32; off > 0; off >>= 1) {
    p10 += __shfl_down(p10, off, 64); p11 += __shfl_down(p11, off, 64);
    p20 += __shfl_down(p20, off, 64); p21 += __shfl_down(p21, off, 64);
    p30 += __shfl_down(p30, off, 64); p31 += __shfl_down(p31, off, 64);
  }
  if (lane == 0) {
    Z1[n * 2 + 0] = p10; Z1[n * 2 + 1] = p11;
    Z2[n * 2 + 0] = p20; Z2[n * 2 + 1] = p21;
    Y1[n * 2 + 0] = tanhf(p30 + mlpb[0]);
    Y1[n * 2 + 1] = tanhf(p31 + mlpb[1]);
  }
}

// ---------------- layer-2 SpMM (2 cols) + final sum ----------------
__global__ __launch_bounds__(256) void spmm2_final(
    const int* __restrict__ rsA, const int* __restrict__ colA, const float* __restrict__ valA,
    const int* __restrict__ rsB, const int* __restrict__ colB, const float* __restrict__ valB,
    const float* __restrict__ Z1, const float* __restrict__ Z2, const float* __restrict__ Y1,
    const float* __restrict__ b2r1, const float* __restrict__ b2r2,
    float* __restrict__ out) {
  int tid = threadIdx.x;
  int lane = tid & 63, wave = tid >> 6;
  int n = blockIdx.x * 4 + wave;
  float a0 = 0.f, a1 = 0.f;
  {
    int s = rsA[n], e = rsA[n + 1];
    for (int i = s + lane; i < e; i += 64) {
      int c = colA[i]; float v = valA[i];
      a0 += v * Z1[c * 2 + 0];
      a1 += v * Z1[c * 2 + 1];
    }
  }
  float c0 = 0.f, c1 = 0.f;
  {
    int s = rsB[n], e = rsB[n + 1];
    for (int i = s + lane; i < e; i += 64) {
      int c = colB[i]; float v = valB[i];
      c0 += v * Z2[c * 2 + 0];
      c1 += v * Z2[c * 2 + 1];
    }
  }
#pragma unroll
  for (int off = 32; off > 0; off >>= 1) {
    a0 += __shfl_down(a0, off, 64); a1 += __shfl_down(a1, off, 64);
    c0 += __shfl_down(c0, off, 64); c1 += __shfl_down(c1, off, 64);
  }
  if (lane == 0) {
    out[n * 2 + 0] = (a0 + b2r1[0]) + (c0 + b2r2[0]) + Y1[n * 2 + 0];
    out[n * 2 + 1] = (a1 + b2r1[1]) + (c1 + b2r2[1]) + Y1[n * 2 + 1];
  }
}

extern "C" void kernel_launch(void* const* d_in, const int* in_sizes, int n_in,
                              void* d_out, int out_size, void* d_ws, size_t ws_size,
                              hipStream_t stream) {
  const float* x        = (const float*)d_in[0];
  const int*   adj_rows = (const int*)d_in[1];
  const int*   adj_cols = (const int*)d_in[2];
  const float* adj_vals = (const float*)d_in[3];
  const int*   s_rows   = (const int*)d_in[4];
  const int*   s_cols   = (const int*)d_in[5];
  const float* s_vals   = (const float*)d_in[6];
  const float* W1r1     = (const float*)d_in[7];
  const float* b1r1     = (const float*)d_in[8];
  const float* W1r2     = (const float*)d_in[9];
  const float* b1r2     = (const float*)d_in[10];
  const float* mlp1_W   = (const float*)d_in[11];
  const float* mlp1_b   = (const float*)d_in[12];
  const float* af1_w    = (const float*)d_in[13];
  const float* W2r1     = (const float*)d_in[14];
  const float* b2r1     = (const float*)d_in[15];
  const float* W2r2     = (const float*)d_in[16];
  const float* b2r2     = (const float*)d_in[17];
  const float* mlp2_W   = (const float*)d_in[18];
  const float* mlp2_b   = (const float*)d_in[19];
  float* out = (float*)d_out;

  char* p = (char*)d_ws;
  auto alloc = [&](size_t b) { char* r = p; p += (b + 255) & ~(size_t)255; return r; };

  // Xb region (76.8 MB) is dead after gemm_mfma; R1/R2/Z1/Z2/Y1 alias into it.
  char* xb_region = alloc((size_t)NN * DIN * 2);
  u16* Xb = (u16*)xb_region;
  u16* R1 = (u16*)xb_region;                                   // 25.6 MB
  u16* R2 = (u16*)(xb_region + (size_t)NN * NH * 2);           // 25.6 MB
  char* zreg = xb_region + (size_t)2 * NN * NH * 2;
  float* Z1 = (float*)zreg;
  float* Z2 = (float*)(zreg + (size_t)NN * 2 * 4);
  float* Y1 = (float*)(zreg + (size_t)NN * 4 * 4);

  u16* H1 = (u16*)alloc((size_t)NN * NH * 2);
  u16* H2 = (u16*)alloc((size_t)NN * NH * 2);
  u16* T  = (u16*)alloc((size_t)NN * NH * 2);
  u16* Wt = (u16*)alloc((size_t)DIN * DIN * 2);
  int*   rsA  = (int*)alloc((size_t)(NN + 1) * 4);
  int*   curA = (int*)alloc((size_t)NN * 4);
  int*   colA = (int*)alloc((size_t)EE * 4);
  float* valA = (float*)alloc((size_t)EE * 4);
  int*   rsB  = (int*)alloc((size_t)(NN + 1) * 4);
  int*   curB = (int*)alloc((size_t)NN * 4);
  int*   colB = (int*)alloc((size_t)EE * 4);
  float* valB = (float*)alloc((size_t)EE * 4);

  // prep
  convert_x<<<37500, 256, 0, stream>>>(x, Xb);
  pack_wt<<<2304, 256, 0, stream>>>(W1r1, W1r2, mlp1_W, Wt);

  // CSR build
  hipMemsetAsync(curA, 0, (size_t)NN * 4, stream);
  hipMemsetAsync(curB, 0, (size_t)NN * 4, stream);
  hist_kernel<<<12500, 256, 0, stream>>>(adj_rows, s_rows, curA, curB);
  scan_kernel<<<2, 1024, 0, stream>>>(curA, rsA, curB, rsB, NN);
  scatter_kernel<<<12500, 256, 0, stream>>>(adj_rows, adj_cols, adj_vals,
                                            s_rows, s_cols, s_vals,
                                            curA, colA, valA, curB, colB, valB);

  // layer-1 fused MFMA GEMM
  dim3 g1(6, (NN + TM - 1) / TM);  // 6 x 391
  gemm_mfma<<<g1, 256, 0, stream>>>(Xb, Wt, mlp1_b, H1, H2, T);

  // layer-1 SpMMs (+bias) — R1/R2 overwrite the now-dead Xb region
  spmm_h<<<NN, 256, 0, stream>>>(rsA, colA, valA, H1, b1r1, R1);
  spmm_h<<<NN, 256, 0, stream>>>(rsB, colB, valB, H2, b1r2, R2);

  // attention fusion -> X1 (in place over R1)
  fusion_kernel<<<NN / 4, 256, 0, stream>>>(R1, R2, T, af1_w, R1);

  // layer-2 dense part
  layer2_gemm<<<NN / 4, 256, 0, stream>>>(R1, W2r1, W2r2, mlp2_W, mlp2_b, Z1, Z2, Y1);

  // layer-2 SpMMs + final sum
  spmm2_final<<<NN / 4, 256, 0, stream>>>(rsA, colA, valA, rsB, colB, valB,
                                          Z1, Z2, Y1, b2r1, b2r2, out);
}

// Round 3
// 1104.362 us; speedup vs baseline: 1.8965x; 1.3295x over previous
//
#include <hip/hip_runtime.h>
#include <hip/hip_bf16.h>

#define NN 50000
#define EE 1600000
#define DIN 768
#define NH 256

typedef unsigned short u16;
typedef unsigned int u32;

typedef __attribute__((ext_vector_type(8))) short short8;
typedef __attribute__((ext_vector_type(4))) float f32x4;

__device__ __forceinline__ float bf2f(u16 u) {
  union { u32 i; float f; } x; x.i = ((u32)u) << 16; return x.f;
}
__device__ __forceinline__ u16 f2bf(float f) {
  union { float f; u32 u; } x; x.f = f;
  u32 r = x.u + 0x7fff + ((x.u >> 16) & 1);  // RNE
  return (u16)(r >> 16);
}

// ---------------- CSR build ----------------
__global__ void hist_kernel(const int* __restrict__ rA, const int* __restrict__ rB,
                            int* __restrict__ cntA, int* __restrict__ cntB) {
  int e = blockIdx.x * 256 + threadIdx.x;
  if (e < EE) atomicAdd(&cntA[rA[e]], 1);
  else        atomicAdd(&cntB[rB[e - EE]], 1);
}

__global__ void scan_kernel(int* __restrict__ cntA, int* __restrict__ rsA,
                            int* __restrict__ cntB, int* __restrict__ rsB, int n) {
  int* cnt = (blockIdx.x == 0) ? cntA : cntB;
  int* rs  = (blockIdx.x == 0) ? rsA  : rsB;
  __shared__ int wsum[16];
  int tid = threadIdx.x, lane = tid & 63, wid = tid >> 6;
  int carry = 0;
  if (tid == 0) rs[0] = 0;
  for (int base = 0; base < n; base += 1024) {
    int i = base + tid;
    int v = (i < n) ? cnt[i] : 0;
    int s = v;
#pragma unroll
    for (int off = 1; off < 64; off <<= 1) {
      int t = __shfl_up(s, off, 64);
      if (lane >= off) s += t;
    }
    if (lane == 63) wsum[wid] = s;
    __syncthreads();
    int wtot = 0;
    for (int w = 0; w < wid; ++w) wtot += wsum[w];
    int incl = carry + wtot + s;
    if (i < n) { rs[i + 1] = incl; cnt[i] = incl - v; }
    int total = 0;
    for (int w = 0; w < 16; ++w) total += wsum[w];
    carry += total;
    __syncthreads();
  }
}

__global__ void scatter_kernel(const int* __restrict__ rA, const int* __restrict__ cA, const float* __restrict__ vA,
                               const int* __restrict__ rB, const int* __restrict__ cB, const float* __restrict__ vB,
                               int* __restrict__ curA, int* __restrict__ colA, float* __restrict__ valA,
                               int* __restrict__ curB, int* __restrict__ colB, float* __restrict__ valB) {
  int e = blockIdx.x * 256 + threadIdx.x;
  if (e < EE) {
    int r = rA[e];
    int p = atomicAdd(&curA[r], 1);
    colA[p] = cA[e]; valA[p] = vA[e];
  } else {
    e -= EE;
    int r = rB[e];
    int p = atomicAdd(&curB[r], 1);
    colB[p] = cB[e]; valB[p] = vB[e];
  }
}

// ---------------- prep: X fp32 -> bf16 ----------------
__global__ __launch_bounds__(256) void convert_x(const float* __restrict__ X, u16* __restrict__ Xb) {
  size_t idx = (size_t)blockIdx.x * 256 + threadIdx.x;
  float4 v = reinterpret_cast<const float4*>(X)[idx];
  ushort4 o;
  o.x = f2bf(v.x); o.y = f2bf(v.y); o.z = f2bf(v.z); o.w = f2bf(v.w);
  reinterpret_cast<ushort4*>(Xb)[idx] = o;
}

// ---------------- prep: pack + transpose weights ----------------
__global__ __launch_bounds__(256) void pack_wt(const float* __restrict__ Wa, const float* __restrict__ Wb,
                                               const float* __restrict__ Wc, u16* __restrict__ Wt) {
  int idx = blockIdx.x * 256 + threadIdx.x;
  int n = idx / DIN, k = idx - n * DIN;
  const float* W = (n < 256) ? Wa : (n < 512) ? Wb : Wc;
  Wt[idx] = f2bf(W[(size_t)k * NH + (n & 255)]);
}

// ---------------- Layer-1 fused MFMA GEMM ----------------
#define TM 128
#define TN 128
#define TK 32

__device__ __forceinline__ void gload16(const u16* g, u16* lds) {
  __builtin_amdgcn_global_load_lds((const __attribute__((address_space(1))) unsigned int*)g,
                                   (__attribute__((address_space(3))) unsigned int*)lds, 16, 0, 0);
}

__global__ __launch_bounds__(256) void gemm_mfma(
    const u16* __restrict__ Xb, const u16* __restrict__ Wt, const float* __restrict__ mlp1_b,
    u16* __restrict__ H1, u16* __restrict__ H2, u16* __restrict__ T) {
  __shared__ u16 As[TM * TK];
  __shared__ u16 Bs[TN * TK];

  const int tid = threadIdx.x;
  const int lane = tid & 63;
  const int w = tid >> 6;
  const int m0 = blockIdx.y * TM;
  const int n0 = blockIdx.x * TN;
  const int wm = w >> 1, wn = w & 1;

  f32x4 acc[4][4] = {};

  const int r_l = lane >> 2;
  const int kcp = lane & 3;
  const int r16 = lane & 15;
  const int kcl = lane >> 4;

  for (int k0 = 0; k0 < DIN; k0 += TK) {
#pragma unroll
    for (int q = 0; q < 2; ++q) {
      int row = w * 32 + q * 16 + r_l;
      int kc = kcp ^ ((row >> 1) & 3);
      int gr = m0 + row; if (gr >= NN) gr = NN - 1;
      gload16(Xb + (size_t)gr * DIN + k0 + kc * 8, &As[(w * 32 + q * 16) * TK]);
      gload16(Wt + (size_t)(n0 + row) * DIN + k0 + kc * 8, &Bs[(w * 32 + q * 16) * TK]);
    }
    __syncthreads();

    short8 aF[4], bF[4];
#pragma unroll
    for (int i = 0; i < 4; ++i) {
      int m = wm * 64 + i * 16 + r16;
      aF[i] = *reinterpret_cast<const short8*>(&As[m * TK + (kcl ^ ((m >> 1) & 3)) * 8]);
      int n = wn * 64 + i * 16 + r16;
      bF[i] = *reinterpret_cast<const short8*>(&Bs[n * TK + (kcl ^ ((n >> 1) & 3)) * 8]);
    }
#pragma unroll
    for (int i = 0; i < 4; ++i)
#pragma unroll
      for (int j = 0; j < 4; ++j)
        acc[i][j] = __builtin_amdgcn_mfma_f32_16x16x32_bf16(aF[i], bF[j], acc[i][j], 0, 0, 0);
    __syncthreads();
  }

  const int bsel = n0 >> 8;
  u16* O = (bsel == 0) ? H1 : (bsel == 1) ? H2 : T;
  const int act = (bsel == 2);
  const int cb = n0 & 255;
  const int rq = lane >> 4;
#pragma unroll
  for (int i = 0; i < 4; ++i) {
#pragma unroll
    for (int r = 0; r < 4; ++r) {
      int grow = m0 + wm * 64 + i * 16 + rq * 4 + r;
      if (grow >= NN) continue;
#pragma unroll
      for (int j = 0; j < 4; ++j) {
        int c = cb + wn * 64 + j * 16 + r16;
        float v = acc[i][j][r];
        if (act) v = tanhf(v + mlp1_b[c]);
        O[(size_t)grow * NH + c] = f2bf(v);
      }
    }
  }
}

// ---------------- SpMM over H=256: 1 wave = 1 row ----------------
// lane = (h-chunk 0..31 of 8 bf16) x (edge group 0..1); 16 B loads, 1 KB/wave-instr.
// grid: (12500, 2) — y selects CSR-A (->R1) or CSR-B (->R2).
__global__ __launch_bounds__(256) void spmm_h2(
    const int* __restrict__ rsA, const int* __restrict__ colA, const float* __restrict__ valA,
    const u16* __restrict__ HA, const float* __restrict__ biasA, u16* __restrict__ outA,
    const int* __restrict__ rsB, const int* __restrict__ colB, const float* __restrict__ valB,
    const u16* __restrict__ HB, const float* __restrict__ biasB, u16* __restrict__ outB) {
  const int* rs; const int* col; const float* val; const u16* H; const float* bias; u16* out;
  if (blockIdx.y == 0) { rs = rsA; col = colA; val = valA; H = HA; bias = biasA; out = outA; }
  else                 { rs = rsB; col = colB; val = valB; H = HB; bias = biasB; out = outB; }

  int tid = threadIdx.x, lane = tid & 63, w = tid >> 6;
  int n = blockIdx.x * 4 + w;
  int h0 = (lane & 31) * 8;
  int eg = lane >> 5;
  int s = rs[n], e = rs[n + 1];
  float acc[8] = {};
  int i = s + eg;
  // 2-deep: two independent 16 B gathers in flight per lane
  for (; i + 2 < e; i += 4) {
    int c0 = col[i], c1 = col[i + 2];
    float v0 = val[i], v1 = val[i + 2];
    short8 hv0 = *reinterpret_cast<const short8*>(H + (size_t)c0 * NH + h0);
    short8 hv1 = *reinterpret_cast<const short8*>(H + (size_t)c1 * NH + h0);
#pragma unroll
    for (int j = 0; j < 8; ++j) acc[j] += v0 * bf2f((u16)hv0[j]);
#pragma unroll
    for (int j = 0; j < 8; ++j) acc[j] += v1 * bf2f((u16)hv1[j]);
  }
  if (i < e) {
    int c0 = col[i];
    float v0 = val[i];
    short8 hv0 = *reinterpret_cast<const short8*>(H + (size_t)c0 * NH + h0);
#pragma unroll
    for (int j = 0; j < 8; ++j) acc[j] += v0 * bf2f((u16)hv0[j]);
  }
#pragma unroll
  for (int j = 0; j < 8; ++j) acc[j] += __shfl_xor(acc[j], 32, 64);
  if (eg == 0) {
    float4 b0 = *reinterpret_cast<const float4*>(bias + h0);
    float4 b1 = *reinterpret_cast<const float4*>(bias + h0 + 4);
    float bb[8] = {b0.x, b0.y, b0.z, b0.w, b1.x, b1.y, b1.z, b1.w};
    short8 o;
#pragma unroll
    for (int j = 0; j < 8; ++j) o[j] = (short)f2bf(acc[j] + bb[j]);
    *reinterpret_cast<short8*>(out + (size_t)n * NH + h0) = o;
  }
}

// ---------------- fused attention fusion + layer-2 GEMV ----------------
// x1 stays in registers (fp32); X1 never materialized.
__global__ __launch_bounds__(256) void fuse_l2(
    const u16* __restrict__ R1, const u16* __restrict__ R2, const u16* __restrict__ T,
    const float* __restrict__ afw,
    const float* __restrict__ W2r1, const float* __restrict__ W2r2,
    const float* __restrict__ mlpW, const float* __restrict__ mlpb,
    float* __restrict__ Z1, float* __restrict__ Z2, float* __restrict__ Y1) {
  __shared__ float w[DIN * 3];
  __shared__ float w1[NH * 2], w2[NH * 2], wm[NH * 2];
  int tid = threadIdx.x;
  for (int i = tid; i < DIN * 3; i += 256) w[i] = afw[i];
  for (int i = tid; i < NH * 2; i += 256) { w1[i] = W2r1[i]; w2[i] = W2r2[i]; wm[i] = mlpW[i]; }
  __syncthreads();
  int lane = tid & 63, wave = tid >> 6;
  int n = blockIdx.x * 4 + wave;
  int h0 = lane * 4;
  ushort4 r1v = *reinterpret_cast<const ushort4*>(R1 + (size_t)n * NH + h0);
  ushort4 r2v = *reinterpret_cast<const ushort4*>(R2 + (size_t)n * NH + h0);
  ushort4 tv  = *reinterpret_cast<const ushort4*>(T  + (size_t)n * NH + h0);
  float r1[4] = {bf2f(r1v.x), bf2f(r1v.y), bf2f(r1v.z), bf2f(r1v.w)};
  float r2[4] = {bf2f(r2v.x), bf2f(r2v.y), bf2f(r2v.z), bf2f(r2v.w)};
  float t[4]  = {bf2f(tv.x),  bf2f(tv.y),  bf2f(tv.z),  bf2f(tv.w)};
  float l0 = 0.f, l1 = 0.f, l2 = 0.f;
#pragma unroll
  for (int i = 0; i < 4; ++i) {
    int h = h0 + i;
    l0 += r1[i] * w[h * 3 + 0] + r2[i] * w[(NH + h) * 3 + 0] + t[i] * w[(2 * NH + h) * 3 + 0];
    l1 += r1[i] * w[h * 3 + 1] + r2[i] * w[(NH + h) * 3 + 1] + t[i] * w[(2 * NH + h) * 3 + 1];
    l2 += r1[i] * w[h * 3 + 2] + r2[i] * w[(NH + h) * 3 + 2] + t[i] * w[(2 * NH + h) * 3 + 2];
  }
#pragma unroll
  for (int off = 32; off > 0; off >>= 1) {
    l0 += __shfl_xor(l0, off, 64);
    l1 += __shfl_xor(l1, off, 64);
    l2 += __shfl_xor(l2, off, 64);
  }
  l0 = fabsf(l0); l1 = fabsf(l1); l2 = fabsf(l2);
  float m = fmaxf(l0, fmaxf(l1, l2));
  float e0 = expf(l0 - m), e1 = expf(l1 - m), e2 = expf(l2 - m);
  float inv = 1.f / (e0 + e1 + e2);
  float a0 = e0 * inv, a1 = e1 * inv, a2 = e2 * inv;

  float p10 = 0.f, p11 = 0.f, p20 = 0.f, p21 = 0.f, p30 = 0.f, p31 = 0.f;
#pragma unroll
  for (int i = 0; i < 4; ++i) {
    int h = h0 + i;
    float xv = a0 * r1[i] + a1 * r2[i] + a2 * t[i];
    p10 += xv * w1[h * 2 + 0]; p11 += xv * w1[h * 2 + 1];
    p20 += xv * w2[h * 2 + 0]; p21 += xv * w2[h * 2 + 1];
    p30 += xv * wm[h * 2 + 0]; p31 += xv * wm[h * 2 + 1];
  }
#pragma unroll
  for (int off = 32; off > 0; off >>= 1) {
    p10 += __shfl_down(p10, off, 64); p11 += __shfl_down(p11, off, 64);
    p20 += __shfl_down(p20, off, 64); p21 += __shfl_down(p21, off, 64);
    p30 += __shfl_down(p30, off, 64); p31 += __shfl_down(p31, off, 64);
  }
  if (lane == 0) {
    Z1[n * 2 + 0] = p10; Z1[n * 2 + 1] = p11;
    Z2[n * 2 + 0] = p20; Z2[n * 2 + 1] = p21;
    Y1[n * 2 + 0] = tanhf(p30 + mlpb[0]);
    Y1[n * 2 + 1] = tanhf(p31 + mlpb[1]);
  }
}

// ---------------- layer-2 SpMM (2 cols) + final sum ----------------
__global__ __launch_bounds__(256) void spmm2_final(
    const int* __restrict__ rsA, const int* __restrict__ colA, const float* __restrict__ valA,
    const int* __restrict__ rsB, const int* __restrict__ colB, const float* __restrict__ valB,
    const float* __restrict__ Z1, const float* __restrict__ Z2, const float* __restrict__ Y1,
    const float* __restrict__ b2r1, const float* __restrict__ b2r2,
    float* __restrict__ out) {
  int tid = threadIdx.x;
  int lane = tid & 63, wave = tid >> 6;
  int n = blockIdx.x * 4 + wave;
  float a0 = 0.f, a1 = 0.f;
  {
    int s = rsA[n], e = rsA[n + 1];
    for (int i = s + lane; i < e; i += 64) {
      int c = colA[i]; float v = valA[i];
      float2 z = *reinterpret_cast<const float2*>(Z1 + c * 2);
      a0 += v * z.x; a1 += v * z.y;
    }
  }
  float c0 = 0.f, c1 = 0.f;
  {
    int s = rsB[n], e = rsB[n + 1];
    for (int i = s + lane; i < e; i += 64) {
      int c = colB[i]; float v = valB[i];
      float2 z = *reinterpret_cast<const float2*>(Z2 + c * 2);
      c0 += v * z.x; c1 += v * z.y;
    }
  }
#pragma unroll
  for (int off = 32; off > 0; off >>= 1) {
    a0 += __shfl_down(a0, off, 64); a1 += __shfl_down(a1, off, 64);
    c0 += __shfl_down(c0, off, 64); c1 += __shfl_down(c1, off, 64);
  }
  if (lane == 0) {
    out[n * 2 + 0] = (a0 + b2r1[0]) + (c0 + b2r2[0]) + Y1[n * 2 + 0];
    out[n * 2 + 1] = (a1 + b2r1[1]) + (c1 + b2r2[1]) + Y1[n * 2 + 1];
  }
}

extern "C" void kernel_launch(void* const* d_in, const int* in_sizes, int n_in,
                              void* d_out, int out_size, void* d_ws, size_t ws_size,
                              hipStream_t stream) {
  const float* x        = (const float*)d_in[0];
  const int*   adj_rows = (const int*)d_in[1];
  const int*   adj_cols = (const int*)d_in[2];
  const float* adj_vals = (const float*)d_in[3];
  const int*   s_rows   = (const int*)d_in[4];
  const int*   s_cols   = (const int*)d_in[5];
  const float* s_vals   = (const float*)d_in[6];
  const float* W1r1     = (const float*)d_in[7];
  const float* b1r1     = (const float*)d_in[8];
  const float* W1r2     = (const float*)d_in[9];
  const float* b1r2     = (const float*)d_in[10];
  const float* mlp1_W   = (const float*)d_in[11];
  const float* mlp1_b   = (const float*)d_in[12];
  const float* af1_w    = (const float*)d_in[13];
  const float* W2r1     = (const float*)d_in[14];
  const float* b2r1     = (const float*)d_in[15];
  const float* W2r2     = (const float*)d_in[16];
  const float* b2r2     = (const float*)d_in[17];
  const float* mlp2_W   = (const float*)d_in[18];
  const float* mlp2_b   = (const float*)d_in[19];
  float* out = (float*)d_out;

  char* p = (char*)d_ws;
  auto alloc = [&](size_t b) { char* r = p; p += (b + 255) & ~(size_t)255; return r; };

  // Xb region (76.8 MB) is dead after gemm_mfma; R1/R2/Z1/Z2/Y1 alias into it.
  char* xb_region = alloc((size_t)NN * DIN * 2);
  u16* Xb = (u16*)xb_region;
  u16* R1 = (u16*)xb_region;
  u16* R2 = (u16*)(xb_region + (size_t)NN * NH * 2);
  char* zreg = xb_region + (size_t)2 * NN * NH * 2;
  float* Z1 = (float*)zreg;
  float* Z2 = (float*)(zreg + (size_t)NN * 2 * 4);
  float* Y1 = (float*)(zreg + (size_t)NN * 4 * 4);

  u16* H1 = (u16*)alloc((size_t)NN * NH * 2);
  u16* H2 = (u16*)alloc((size_t)NN * NH * 2);
  u16* T  = (u16*)alloc((size_t)NN * NH * 2);
  u16* Wt = (u16*)alloc((size_t)DIN * DIN * 2);
  int*   rsA  = (int*)alloc((size_t)(NN + 1) * 4);
  int*   curA = (int*)alloc((size_t)NN * 4);
  int*   colA = (int*)alloc((size_t)EE * 4);
  float* valA = (float*)alloc((size_t)EE * 4);
  int*   rsB  = (int*)alloc((size_t)(NN + 1) * 4);
  int*   curB = (int*)alloc((size_t)NN * 4);
  int*   colB = (int*)alloc((size_t)EE * 4);
  float* valB = (float*)alloc((size_t)EE * 4);

  // prep
  convert_x<<<37500, 256, 0, stream>>>(x, Xb);
  pack_wt<<<2304, 256, 0, stream>>>(W1r1, W1r2, mlp1_W, Wt);

  // CSR build
  hipMemsetAsync(curA, 0, (size_t)NN * 4, stream);
  hipMemsetAsync(curB, 0, (size_t)NN * 4, stream);
  hist_kernel<<<12500, 256, 0, stream>>>(adj_rows, s_rows, curA, curB);
  scan_kernel<<<2, 1024, 0, stream>>>(curA, rsA, curB, rsB, NN);
  scatter_kernel<<<12500, 256, 0, stream>>>(adj_rows, adj_cols, adj_vals,
                                            s_rows, s_cols, s_vals,
                                            curA, colA, valA, curB, colB, valB);

  // layer-1 fused MFMA GEMM
  dim3 g1(6, (NN + TM - 1) / TM);
  gemm_mfma<<<g1, 256, 0, stream>>>(Xb, Wt, mlp1_b, H1, H2, T);

  // layer-1 SpMMs, both in one dispatch (R1/R2 overwrite dead Xb region)
  dim3 gs(12500, 2);
  spmm_h2<<<gs, 256, 0, stream>>>(rsA, colA, valA, H1, b1r1, R1,
                                  rsB, colB, valB, H2, b1r2, R2);

  // fused attention + layer-2 dense
  fuse_l2<<<NN / 4, 256, 0, stream>>>(R1, R2, T, af1_w, W2r1, W2r2, mlp2_W, mlp2_b,
                                      Z1, Z2, Y1);

  // layer-2 SpMMs + final sum
  spmm2_final<<<NN / 4, 256, 0, stream>>>(rsA, colA, valA, rsB, colB, valB,
                                          Z1, Z2, Y1, b2r1, b2r2, out);
}

// Round 4
// 943.118 us; speedup vs baseline: 2.2208x; 1.1710x over previous
//
#include <hip/hip_runtime.h>
#include <hip/hip_bf16.h>

#define NN 50000
#define EE 1600000
#define DIN 768
#define NH 256

typedef unsigned short u16;
typedef unsigned int u32;

typedef __attribute__((ext_vector_type(8))) short short8;
typedef __attribute__((ext_vector_type(4))) float f32x4;

__device__ __forceinline__ float bf2f(u16 u) {
  union { u32 i; float f; } x; x.i = ((u32)u) << 16; return x.f;
}
__device__ __forceinline__ u16 f2bf(float f) {
  union { float f; u32 u; } x; x.f = f;
  u32 r = x.u + 0x7fff + ((x.u >> 16) & 1);  // RNE
  return (u16)(r >> 16);
}

// ---------------- fused prep: convert_x + hist + pack_wt ----------------
// blocks [0,37500): X fp32->bf16 (float4/ushort4)
// blocks [37500,50000): histogram of both row arrays (2E atomics)
// blocks [50000,52304): pack+transpose the 3 weight mats to bf16 Wt[768][768]
__global__ __launch_bounds__(256) void prep_kernel(
    const float* __restrict__ X, u16* __restrict__ Xb,
    const int* __restrict__ rA, const int* __restrict__ rB,
    int* __restrict__ cntA, int* __restrict__ cntB,
    const float* __restrict__ Wa, const float* __restrict__ Wb,
    const float* __restrict__ Wc, u16* __restrict__ Wt) {
  int b = blockIdx.x;
  if (b < 37500) {
    size_t idx = (size_t)b * 256 + threadIdx.x;
    float4 v = reinterpret_cast<const float4*>(X)[idx];
    ushort4 o;
    o.x = f2bf(v.x); o.y = f2bf(v.y); o.z = f2bf(v.z); o.w = f2bf(v.w);
    reinterpret_cast<ushort4*>(Xb)[idx] = o;
  } else if (b < 50000) {
    int e = (b - 37500) * 256 + threadIdx.x;
    if (e < EE) atomicAdd(&cntA[rA[e]], 1);
    else        atomicAdd(&cntB[rB[e - EE]], 1);
  } else {
    int idx = (b - 50000) * 256 + threadIdx.x;
    int n = idx / DIN, k = idx - n * DIN;
    const float* W = (n < 256) ? Wa : (n < 512) ? Wb : Wc;
    Wt[idx] = f2bf(W[(size_t)k * NH + (n & 255)]);
  }
}

// ---------------- 3-phase scan (both CSRs via blockIdx.y) ----------------
// phase 1: per-512-chunk scan; cnt[i] <- excl-in-block, rs[i+1] <- incl-in-block
__global__ __launch_bounds__(256) void scan1(int* __restrict__ cntA, int* __restrict__ rsA,
                                             int* __restrict__ cntB, int* __restrict__ rsB,
                                             int* __restrict__ bsum) {
  int* cnt = (blockIdx.y == 0) ? cntA : cntB;
  int* rs  = (blockIdx.y == 0) ? rsA  : rsB;
  int* bs  = bsum + blockIdx.y * 98;
  __shared__ int wsum[4];
  int t = threadIdx.x, lane = t & 63, wid = t >> 6;
  int i0 = blockIdx.x * 512 + 2 * t;
  int v0 = (i0 < NN) ? cnt[i0] : 0;
  int v1 = (i0 + 1 < NN) ? cnt[i0 + 1] : 0;
  int s = v0 + v1;
  int sc = s;
#pragma unroll
  for (int off = 1; off < 64; off <<= 1) {
    int tv = __shfl_up(sc, off, 64);
    if (lane >= off) sc += tv;
  }
  if (lane == 63) wsum[wid] = sc;
  __syncthreads();
  int woff = 0;
  for (int w = 0; w < wid; ++w) woff += wsum[w];
  int excl = woff + sc - s;
  if (i0 < NN)     { cnt[i0] = excl;          rs[i0 + 1] = excl + v0; }
  if (i0 + 1 < NN) { cnt[i0 + 1] = excl + v0; rs[i0 + 2] = excl + v0 + v1; }
  if (t == 255) bs[blockIdx.x] = woff + sc;
  if (blockIdx.x == 0 && t == 0) rs[0] = 0;
}

// phase 2: exclusive scan of the 98 block totals (per CSR)
__global__ __launch_bounds__(128) void scan2(int* __restrict__ bsum) {
  int* bs = bsum + blockIdx.y * 98;
  __shared__ int tmp[128];
  int t = threadIdx.x;
  int orig = (t < 98) ? bs[t] : 0;
  tmp[t] = orig;
  __syncthreads();
  for (int off = 1; off < 128; off <<= 1) {
    int v = (t >= off) ? tmp[t - off] : 0;
    __syncthreads();
    tmp[t] += v;
    __syncthreads();
  }
  if (t < 98) bs[t] = tmp[t] - orig;
}

// phase 3: add block offsets
__global__ __launch_bounds__(512) void scan3(int* __restrict__ cntA, int* __restrict__ rsA,
                                             int* __restrict__ cntB, int* __restrict__ rsB,
                                             const int* __restrict__ bsum) {
  int* cnt = (blockIdx.y == 0) ? cntA : cntB;
  int* rs  = (blockIdx.y == 0) ? rsA  : rsB;
  int off = bsum[blockIdx.y * 98 + blockIdx.x];
  int i = blockIdx.x * 512 + threadIdx.x;
  if (i < NN) { cnt[i] += off; rs[i + 1] += off; }
}

// ---------------- fused layer-1 MFMA GEMM + CSR scatter ----------------
#define TM 128
#define TN 128
#define TK 32
#define GEMM_BLKS 2346           // 6 * 391
#define TOT_BLKS (GEMM_BLKS + 12500)

__device__ __forceinline__ void gload16(const u16* g, u16* lds) {
  __builtin_amdgcn_global_load_lds((const __attribute__((address_space(1))) unsigned int*)g,
                                   (__attribute__((address_space(3))) unsigned int*)lds, 16, 0, 0);
}

__global__ __launch_bounds__(256) void gemm_scatter(
    const u16* __restrict__ Xb, const u16* __restrict__ Wt, const float* __restrict__ mlp1_b,
    u16* __restrict__ H1, u16* __restrict__ H2, u16* __restrict__ T,
    const int* __restrict__ rA, const int* __restrict__ cA, const float* __restrict__ vA,
    const int* __restrict__ rB, const int* __restrict__ cB, const float* __restrict__ vB,
    int* __restrict__ curA, int2* __restrict__ edgeA,
    int* __restrict__ curB, int2* __restrict__ edgeB) {
  __shared__ u16 As[TM * TK];
  __shared__ u16 Bs[TN * TK];

  const int b = blockIdx.x;
  // interleave: exactly GEMM_BLKS gemm blocks spread evenly over TOT_BLKS
  const int lo = (b * GEMM_BLKS) / TOT_BLKS;
  const int hi = ((b + 1) * GEMM_BLKS) / TOT_BLKS;

  if (hi > lo) {
    // ---- GEMM block (gid = lo in [0, 2346)) ----
    const int gid = lo;
    const int tid = threadIdx.x;
    const int lane = tid & 63;
    const int w = tid >> 6;
    const int n0 = (gid % 6) * TN;
    const int m0 = (gid / 6) * TM;
    const int wm = w >> 1, wn = w & 1;

    f32x4 acc[4][4] = {};

    const int r_l = lane >> 2;
    const int kcp = lane & 3;
    const int r16 = lane & 15;
    const int kcl = lane >> 4;

    for (int k0 = 0; k0 < DIN; k0 += TK) {
#pragma unroll
      for (int q = 0; q < 2; ++q) {
        int row = w * 32 + q * 16 + r_l;
        int kc = kcp ^ ((row >> 1) & 3);
        int gr = m0 + row; if (gr >= NN) gr = NN - 1;
        gload16(Xb + (size_t)gr * DIN + k0 + kc * 8, &As[(w * 32 + q * 16) * TK]);
        gload16(Wt + (size_t)(n0 + row) * DIN + k0 + kc * 8, &Bs[(w * 32 + q * 16) * TK]);
      }
      __syncthreads();

      short8 aF[4], bF[4];
#pragma unroll
      for (int i = 0; i < 4; ++i) {
        int m = wm * 64 + i * 16 + r16;
        aF[i] = *reinterpret_cast<const short8*>(&As[m * TK + (kcl ^ ((m >> 1) & 3)) * 8]);
        int n = wn * 64 + i * 16 + r16;
        bF[i] = *reinterpret_cast<const short8*>(&Bs[n * TK + (kcl ^ ((n >> 1) & 3)) * 8]);
      }
#pragma unroll
      for (int i = 0; i < 4; ++i)
#pragma unroll
        for (int j = 0; j < 4; ++j)
          acc[i][j] = __builtin_amdgcn_mfma_f32_16x16x32_bf16(aF[i], bF[j], acc[i][j], 0, 0, 0);
      __syncthreads();
    }

    const int bsel = n0 >> 8;
    u16* O = (bsel == 0) ? H1 : (bsel == 1) ? H2 : T;
    const int act = (bsel == 2);
    const int cb = n0 & 255;
    const int rq = lane >> 4;
#pragma unroll
    for (int i = 0; i < 4; ++i) {
#pragma unroll
      for (int r = 0; r < 4; ++r) {
        int grow = m0 + wm * 64 + i * 16 + rq * 4 + r;
        if (grow >= NN) continue;
#pragma unroll
        for (int j = 0; j < 4; ++j) {
          int c = cb + wn * 64 + j * 16 + r16;
          float v = acc[i][j][r];
          if (act) v = tanhf(v + mlp1_b[c]);
          O[(size_t)grow * NH + c] = f2bf(v);
        }
      }
    }
  } else {
    // ---- scatter block (sid in [0, 12500)) ----
    const int sid = b - lo;
    int e = sid * 256 + threadIdx.x;
    if (e < EE) {
      int r = rA[e];
      int p = atomicAdd(&curA[r], 1);
      int2 o; o.x = cA[e]; o.y = __float_as_int(vA[e]);
      edgeA[p] = o;
    } else {
      e -= EE;
      int r = rB[e];
      int p = atomicAdd(&curB[r], 1);
      int2 o; o.x = cB[e]; o.y = __float_as_int(vB[e]);
      edgeB[p] = o;
    }
  }
}

// ---------------- SpMM over H=256: 1 wave = 1 row ----------------
__global__ __launch_bounds__(256) void spmm_h2(
    const int* __restrict__ rsA, const int2* __restrict__ edgeA,
    const u16* __restrict__ HA, const float* __restrict__ biasA, u16* __restrict__ outA,
    const int* __restrict__ rsB, const int2* __restrict__ edgeB,
    const u16* __restrict__ HB, const float* __restrict__ biasB, u16* __restrict__ outB) {
  const int* rs; const int2* edge; const u16* H; const float* bias; u16* out;
  if (blockIdx.y == 0) { rs = rsA; edge = edgeA; H = HA; bias = biasA; out = outA; }
  else                 { rs = rsB; edge = edgeB; H = HB; bias = biasB; out = outB; }

  int tid = threadIdx.x, lane = tid & 63, w = tid >> 6;
  int n = blockIdx.x * 4 + w;
  int h0 = (lane & 31) * 8;
  int eg = lane >> 5;
  int s = rs[n], e = rs[n + 1];
  float acc[8] = {};
  int i = s + eg;
  for (; i + 2 < e; i += 4) {
    int2 e0 = edge[i], e1 = edge[i + 2];
    float v0 = __int_as_float(e0.y), v1 = __int_as_float(e1.y);
    short8 hv0 = *reinterpret_cast<const short8*>(H + (size_t)e0.x * NH + h0);
    short8 hv1 = *reinterpret_cast<const short8*>(H + (size_t)e1.x * NH + h0);
#pragma unroll
    for (int j = 0; j < 8; ++j) acc[j] += v0 * bf2f((u16)hv0[j]);
#pragma unroll
    for (int j = 0; j < 8; ++j) acc[j] += v1 * bf2f((u16)hv1[j]);
  }
  if (i < e) {
    int2 e0 = edge[i];
    float v0 = __int_as_float(e0.y);
    short8 hv0 = *reinterpret_cast<const short8*>(H + (size_t)e0.x * NH + h0);
#pragma unroll
    for (int j = 0; j < 8; ++j) acc[j] += v0 * bf2f((u16)hv0[j]);
  }
#pragma unroll
  for (int j = 0; j < 8; ++j) acc[j] += __shfl_xor(acc[j], 32, 64);
  if (eg == 0) {
    float4 b0 = *reinterpret_cast<const float4*>(bias + h0);
    float4 b1 = *reinterpret_cast<const float4*>(bias + h0 + 4);
    float bb[8] = {b0.x, b0.y, b0.z, b0.w, b1.x, b1.y, b1.z, b1.w};
    short8 o;
#pragma unroll
    for (int j = 0; j < 8; ++j) o[j] = (short)f2bf(acc[j] + bb[j]);
    *reinterpret_cast<short8*>(out + (size_t)n * NH + h0) = o;
  }
}

// ---------------- fused attention fusion + layer-2 GEMV ----------------
__global__ __launch_bounds__(256) void fuse_l2(
    const u16* __restrict__ R1, const u16* __restrict__ R2, const u16* __restrict__ T,
    const float* __restrict__ afw,
    const float* __restrict__ W2r1, const float* __restrict__ W2r2,
    const float* __restrict__ mlpW, const float* __restrict__ mlpb,
    float* __restrict__ Z1, float* __restrict__ Z2, float* __restrict__ Y1) {
  __shared__ float w[DIN * 3];
  __shared__ float w1[NH * 2], w2[NH * 2], wm[NH * 2];
  int tid = threadIdx.x;
  for (int i = tid; i < DIN * 3; i += 256) w[i] = afw[i];
  for (int i = tid; i < NH * 2; i += 256) { w1[i] = W2r1[i]; w2[i] = W2r2[i]; wm[i] = mlpW[i]; }
  __syncthreads();
  int lane = tid & 63, wave = tid >> 6;
  int n = blockIdx.x * 4 + wave;
  int h0 = lane * 4;
  ushort4 r1v = *reinterpret_cast<const ushort4*>(R1 + (size_t)n * NH + h0);
  ushort4 r2v = *reinterpret_cast<const ushort4*>(R2 + (size_t)n * NH + h0);
  ushort4 tv  = *reinterpret_cast<const ushort4*>(T  + (size_t)n * NH + h0);
  float r1[4] = {bf2f(r1v.x), bf2f(r1v.y), bf2f(r1v.z), bf2f(r1v.w)};
  float r2[4] = {bf2f(r2v.x), bf2f(r2v.y), bf2f(r2v.z), bf2f(r2v.w)};
  float t[4]  = {bf2f(tv.x),  bf2f(tv.y),  bf2f(tv.z),  bf2f(tv.w)};
  float l0 = 0.f, l1 = 0.f, l2 = 0.f;
#pragma unroll
  for (int i = 0; i < 4; ++i) {
    int h = h0 + i;
    l0 += r1[i] * w[h * 3 + 0] + r2[i] * w[(NH + h) * 3 + 0] + t[i] * w[(2 * NH + h) * 3 + 0];
    l1 += r1[i] * w[h * 3 + 1] + r2[i] * w[(NH + h) * 3 + 1] + t[i] * w[(2 * NH + h) * 3 + 1];
    l2 += r1[i] * w[h * 3 + 2] + r2[i] * w[(NH + h) * 3 + 2] + t[i] * w[(2 * NH + h) * 3 + 2];
  }
#pragma unroll
  for (int off = 32; off > 0; off >>= 1) {
    l0 += __shfl_xor(l0, off, 64);
    l1 += __shfl_xor(l1, off, 64);
    l2 += __shfl_xor(l2, off, 64);
  }
  l0 = fabsf(l0); l1 = fabsf(l1); l2 = fabsf(l2);
  float m = fmaxf(l0, fmaxf(l1, l2));
  float e0 = expf(l0 - m), e1 = expf(l1 - m), e2 = expf(l2 - m);
  float inv = 1.f / (e0 + e1 + e2);
  float a0 = e0 * inv, a1 = e1 * inv, a2 = e2 * inv;

  float p10 = 0.f, p11 = 0.f, p20 = 0.f, p21 = 0.f, p30 = 0.f, p31 = 0.f;
#pragma unroll
  for (int i = 0; i < 4; ++i) {
    int h = h0 + i;
    float xv = a0 * r1[i] + a1 * r2[i] + a2 * t[i];
    p10 += xv * w1[h * 2 + 0]; p11 += xv * w1[h * 2 + 1];
    p20 += xv * w2[h * 2 + 0]; p21 += xv * w2[h * 2 + 1];
    p30 += xv * wm[h * 2 + 0]; p31 += xv * wm[h * 2 + 1];
  }
#pragma unroll
  for (int off = 32; off > 0; off >>= 1) {
    p10 += __shfl_down(p10, off, 64); p11 += __shfl_down(p11, off, 64);
    p20 += __shfl_down(p20, off, 64); p21 += __shfl_down(p21, off, 64);
    p30 += __shfl_down(p30, off, 64); p31 += __shfl_down(p31, off, 64);
  }
  if (lane == 0) {
    Z1[n * 2 + 0] = p10; Z1[n * 2 + 1] = p11;
    Z2[n * 2 + 0] = p20; Z2[n * 2 + 1] = p21;
    Y1[n * 2 + 0] = tanhf(p30 + mlpb[0]);
    Y1[n * 2 + 1] = tanhf(p31 + mlpb[1]);
  }
}

// ---------------- layer-2 SpMM (2 cols) + final sum ----------------
__global__ __launch_bounds__(256) void spmm2_final(
    const int* __restrict__ rsA, const int2* __restrict__ edgeA,
    const int* __restrict__ rsB, const int2* __restrict__ edgeB,
    const float* __restrict__ Z1, const float* __restrict__ Z2, const float* __restrict__ Y1,
    const float* __restrict__ b2r1, const float* __restrict__ b2r2,
    float* __restrict__ out) {
  int tid = threadIdx.x;
  int lane = tid & 63, wave = tid >> 6;
  int n = blockIdx.x * 4 + wave;
  float a0 = 0.f, a1 = 0.f;
  {
    int s = rsA[n], e = rsA[n + 1];
    for (int i = s + lane; i < e; i += 64) {
      int2 ed = edgeA[i];
      float v = __int_as_float(ed.y);
      float2 z = *reinterpret_cast<const float2*>(Z1 + ed.x * 2);
      a0 += v * z.x; a1 += v * z.y;
    }
  }
  float c0 = 0.f, c1 = 0.f;
  {
    int s = rsB[n], e = rsB[n + 1];
    for (int i = s + lane; i < e; i += 64) {
      int2 ed = edgeB[i];
      float v = __int_as_float(ed.y);
      float2 z = *reinterpret_cast<const float2*>(Z2 + ed.x * 2);
      c0 += v * z.x; c1 += v * z.y;
    }
  }
#pragma unroll
  for (int off = 32; off > 0; off >>= 1) {
    a0 += __shfl_down(a0, off, 64); a1 += __shfl_down(a1, off, 64);
    c0 += __shfl_down(c0, off, 64); c1 += __shfl_down(c1, off, 64);
  }
  if (lane == 0) {
    out[n * 2 + 0] = (a0 + b2r1[0]) + (c0 + b2r2[0]) + Y1[n * 2 + 0];
    out[n * 2 + 1] = (a1 + b2r1[1]) + (c1 + b2r2[1]) + Y1[n * 2 + 1];
  }
}

extern "C" void kernel_launch(void* const* d_in, const int* in_sizes, int n_in,
                              void* d_out, int out_size, void* d_ws, size_t ws_size,
                              hipStream_t stream) {
  const float* x        = (const float*)d_in[0];
  const int*   adj_rows = (const int*)d_in[1];
  const int*   adj_cols = (const int*)d_in[2];
  const float* adj_vals = (const float*)d_in[3];
  const int*   s_rows   = (const int*)d_in[4];
  const int*   s_cols   = (const int*)d_in[5];
  const float* s_vals   = (const float*)d_in[6];
  const float* W1r1     = (const float*)d_in[7];
  const float* b1r1     = (const float*)d_in[8];
  const float* W1r2     = (const float*)d_in[9];
  const float* b1r2     = (const float*)d_in[10];
  const float* mlp1_W   = (const float*)d_in[11];
  const float* mlp1_b   = (const float*)d_in[12];
  const float* af1_w    = (const float*)d_in[13];
  const float* W2r1     = (const float*)d_in[14];
  const float* b2r1     = (const float*)d_in[15];
  const float* W2r2     = (const float*)d_in[16];
  const float* b2r2     = (const float*)d_in[17];
  const float* mlp2_W   = (const float*)d_in[18];
  const float* mlp2_b   = (const float*)d_in[19];
  float* out = (float*)d_out;

  char* p = (char*)d_ws;
  auto alloc = [&](size_t b) { char* r = p; p += (b + 255) & ~(size_t)255; return r; };

  // Xb region (76.8 MB) is dead after gemm; R1/R2/Z1/Z2/Y1 alias into it.
  char* xb_region = alloc((size_t)NN * DIN * 2);
  u16* Xb = (u16*)xb_region;
  u16* R1 = (u16*)xb_region;
  u16* R2 = (u16*)(xb_region + (size_t)NN * NH * 2);
  char* zreg = xb_region + (size_t)2 * NN * NH * 2;
  float* Z1 = (float*)zreg;
  float* Z2 = (float*)(zreg + (size_t)NN * 2 * 4);
  float* Y1 = (float*)(zreg + (size_t)NN * 4 * 4);

  u16* H1 = (u16*)alloc((size_t)NN * NH * 2);
  u16* H2 = (u16*)alloc((size_t)NN * NH * 2);
  u16* T  = (u16*)alloc((size_t)NN * NH * 2);
  u16* Wt = (u16*)alloc((size_t)DIN * DIN * 2);
  int*  rsA   = (int*)alloc((size_t)(NN + 1) * 4);
  int*  curA  = (int*)alloc((size_t)NN * 4);
  int2* edgeA = (int2*)alloc((size_t)EE * 8);
  int*  rsB   = (int*)alloc((size_t)(NN + 1) * 4);
  int*  curB  = (int*)alloc((size_t)NN * 4);
  int2* edgeB = (int2*)alloc((size_t)EE * 8);
  int*  bsum  = (int*)alloc(2 * 98 * 4);

  // counters zero + fused prep (convert_x | hist | pack_wt)
  hipMemsetAsync(curA, 0, (size_t)NN * 4, stream);
  hipMemsetAsync(curB, 0, (size_t)NN * 4, stream);
  prep_kernel<<<52304, 256, 0, stream>>>(x, Xb, adj_rows, s_rows, curA, curB,
                                         W1r1, W1r2, mlp1_W, Wt);

  // 3-phase scan -> rs + exclusive cursors (both CSRs)
  dim3 gsc(98, 2);
  scan1<<<gsc, 256, 0, stream>>>(curA, rsA, curB, rsB, bsum);
  scan2<<<dim3(1, 2), 128, 0, stream>>>(bsum);
  scan3<<<gsc, 512, 0, stream>>>(curA, rsA, curB, rsB, bsum);

  // fused layer-1 GEMM + CSR scatter (interleaved block mix)
  gemm_scatter<<<TOT_BLKS, 256, 0, stream>>>(Xb, Wt, mlp1_b, H1, H2, T,
                                             adj_rows, adj_cols, adj_vals,
                                             s_rows, s_cols, s_vals,
                                             curA, edgeA, curB, edgeB);

  // layer-1 SpMMs, both in one dispatch (R1/R2 overwrite dead Xb region)
  dim3 gs(12500, 2);
  spmm_h2<<<gs, 256, 0, stream>>>(rsA, edgeA, H1, b1r1, R1,
                                  rsB, edgeB, H2, b1r2, R2);

  // fused attention + layer-2 dense
  fuse_l2<<<NN / 4, 256, 0, stream>>>(R1, R2, T, af1_w, W2r1, W2r2, mlp2_W, mlp2_b,
                                      Z1, Z2, Y1);

  // layer-2 SpMMs + final sum
  spmm2_final<<<NN / 4, 256, 0, stream>>>(rsA, edgeA, rsB, edgeB,
                                          Z1, Z2, Y1, b2r1, b2r2, out);
}